// Round 11
// baseline (290.844 us; speedup 1.0000x reference)
//
#include <hip/hip_runtime.h>
#include <hip/hip_bf16.h>
#include <hip/hip_cooperative_groups.h>

namespace cg = cooperative_groups;

#define KDIM 1024
#define NDIM 1024
#define NEXP 8
#define TTOK 8192
#define NT (KDIM / 32)

typedef __bf16 bf16x8 __attribute__((ext_vector_type(8)));
typedef __bf16 bf16x4 __attribute__((ext_vector_type(4)));
typedef float  f32x4  __attribute__((ext_vector_type(4)));

__device__ __forceinline__ void gl2lds16(const void* g, void* l) {
  __builtin_amdgcn_global_load_lds(
      (const __attribute__((address_space(1))) void*)g,
      (__attribute__((address_space(3))) void*)l, 16, 0, 0);
}

// Fragment-swizzled layouts (16B per lane-slot):
//   swA slot(panel,kt,lane) = x[panel*16 + (lane&15)][kt*32 + (lane>>4)*8 .. +8]
//   swB slot(e,panel,kt,lane) = W[e][kt*32 + (lane>>4)*8 .. +8][panel*16 + (lane&15)]

// ---------------- FUSED: prepass (grid-stride) -> grid.sync -> GEMM ----------------
// Rationale (r10 accounting): fills ~83us harness-fixed; prepass ~17us (~BW floor);
// GEMM ~30us (= 2-phase-counted grouped ceiling, m248; 8-phase is 256^2-gated and
// 256^2 tiles don't fit N=1024 x ragged-M). Remaining controllable: the ~4-6us of
// second-launch overhead + prepass tail-drain + GEMM ramp -> fuse with cooperative
// grid sync (sanctioned harness mechanism; device-scope handoff across XCDs).
// Phase 1 = round-10 prepass bodies, grid-strided 3072 virtual blocks over 576 real.
// Phase 2 = round-10 GEMM byte-identical. Lt (9 KB) aliases into buf (48 KB).
__global__ __launch_bounds__(256, 3) void moe_fused(
    const float* __restrict__ x, const float* __restrict__ W,
    const int* __restrict__ gs, const float* __restrict__ bias,
    __bf16* __restrict__ swA, __bf16* __restrict__ swB,
    float* __restrict__ out)
{
  __shared__ __align__(16) __bf16 buf[3][8192];   // 48 KB; phase 1 uses first 9 KB as Lt
  const int t = threadIdx.x;

  // ======== phase 1: prepass ========
  {
    __bf16* Lt = &buf[0][0];                      // 64*72 = 4608 elems
    for (int vb = blockIdx.x; vb < 3072; vb += gridDim.x) {
      if (vb < 1024) {
        // x fp32 -> swA bf16 (fragment-swizzled); fully coalesced both sides
#pragma unroll
        for (int p = 0; p < 4; ++p) {
          int s = vb * 1024 + p * 256 + t;
          int lane = s & 63, kt = (s >> 6) & 31, panel = s >> 11;
          int row = panel * 16 + (lane & 15);
          int k0 = kt * 32 + ((lane >> 4) << 3);
          const float* xp = x + (size_t)row * KDIM + k0;
          float4 a = *(const float4*)xp;
          float4 b = *(const float4*)(xp + 4);
          bf16x8 v;
          v[0] = (__bf16)a.x; v[1] = (__bf16)a.y; v[2] = (__bf16)a.z; v[3] = (__bf16)a.w;
          v[4] = (__bf16)b.x; v[5] = (__bf16)b.y; v[6] = (__bf16)b.z; v[7] = (__bf16)b.w;
          *(bf16x8*)(swA + (size_t)s * 8) = v;
        }
      } else {
        // W fp32 -> swB bf16 transposed (LDS-staged 64x64 tile)
        int bid = vb - 1024;
        int e = bid >> 8, r = bid & 255;
        int k0 = (r >> 4) * 64, n0 = (r & 15) * 64;
        const float* Wp = W + (size_t)e * KDIM * NDIM;
        int rr0 = t >> 4, c4 = t & 15;
        __syncthreads();                          // protect Lt vs previous iteration's reads
#pragma unroll
        for (int p = 0; p < 4; ++p) {
          int kk = rr0 + p * 16;
          float4 v = *(const float4*)(Wp + (size_t)(k0 + kk) * NDIM + n0 + c4 * 4);
          Lt[(c4 * 4 + 0) * 72 + kk] = (__bf16)v.x;
          Lt[(c4 * 4 + 1) * 72 + kk] = (__bf16)v.y;
          Lt[(c4 * 4 + 2) * 72 + kk] = (__bf16)v.z;
          Lt[(c4 * 4 + 3) * 72 + kk] = (__bf16)v.w;
        }
        __syncthreads();
#pragma unroll
        for (int q = 0; q < 2; ++q) {
          int slot = q * 256 + t;
          int lane = slot & 63, grp = slot >> 6;
          int np = grp & 3, kt2 = grp >> 2;
          int nl = np * 16 + (lane & 15);
          int kl = kt2 * 32 + ((lane >> 4) << 3);
          bf16x8 v = *(const bf16x8*)(Lt + nl * 72 + kl);
          int panel = (n0 >> 4) + np;
          int ktg = (k0 >> 5) + kt2;
          size_t sg = (((size_t)e * 64 + panel) * 32 + ktg) * 64 + lane;
          *(bf16x8*)(swB + sg * 8) = v;
        }
      }
    }
  }

  __threadfence();                                // device-scope release of swA/swB
  cg::this_grid().sync();                         // all prepass writes visible grid-wide

  // ======== phase 2: GEMM (round-10 body, proven 132.2) ========
  const int b = blockIdx.x;
  const int xcd = b & 7, bi = b >> 3;
  int y = xcd * 9 + bi % 9;           // global m-tile index (XCD-contiguous m-ranges)
  const int nt = bi / 9;

  int e = 0, tile0 = 0, lo = 0, hi = 0, found = 0, off = 0;
#pragma unroll
  for (int i = 0; i < NEXP; ++i) {
    int g = gs[i];
    int first = off >> 7;
    int cnt = (g > 0) ? (((off + g - 1) >> 7) - first + 1) : 0;
    if (!found) {
      if (y < cnt) {
        found = 1; e = i; tile0 = (first + y) << 7;
        lo = max(tile0, off); hi = min(tile0 + 128, off + g);
      } else y -= cnt;
    }
    off += g;
  }
  if (!found) return;                       // after grid.sync: no barrier mismatch
  const int n0 = nt * 128;

  const int lane = t & 63, wv = t >> 6;
  const int wm = wv & 1, wn = wv >> 1, lm = lane & 15, lg = lane >> 4;

  const __bf16* gA0 = swA + (size_t)((tile0 >> 4) + wv) * 16384 + lane * 8;
  const __bf16* gA1 = swA + (size_t)((tile0 >> 4) + 4 + wv) * 16384 + lane * 8;
  const __bf16* gB0 = swB + (size_t)(e * 64 + (n0 >> 4) + wv) * 16384 + lane * 8;
  const __bf16* gB1 = swB + (size_t)(e * 64 + (n0 >> 4) + 4 + wv) * 16384 + lane * 8;

  auto stage = [&](int kt, int sb) {
    __bf16* l = &buf[sb][0];
    const int ko = kt * 512;
    gl2lds16(gA0 + ko, l + (size_t)(0 * 256 + wv * 64) * 8);   // A panel wv
    gl2lds16(gA1 + ko, l + (size_t)(1 * 256 + wv * 64) * 8);   // A panel 4+wv
    gl2lds16(gB0 + ko, l + (size_t)(2 * 256 + wv * 64) * 8);   // B panel wv
    gl2lds16(gB1 + ko, l + (size_t)(3 * 256 + wv * 64) * 8);   // B panel 4+wv
  };

  f32x4 acc[4][4] = {};
  auto compute = [&](const __bf16* l) {
    bf16x8 aF[4], bF[4];
#pragma unroll
    for (int i = 0; i < 4; ++i)
      aF[i] = *(const bf16x8*)(l + (size_t)((wm * 4 + i) * 64 + lane) * 8);
#pragma unroll
    for (int j = 0; j < 4; ++j)
      bF[j] = *(const bf16x8*)(l + 4096 + (size_t)((wn * 4 + j) * 64 + lane) * 8);
#pragma unroll
    for (int i = 0; i < 4; ++i)
#pragma unroll
      for (int j = 0; j < 4; ++j)
        acc[i][j] = __builtin_amdgcn_mfma_f32_16x16x32_bf16(aF[i], bF[j], acc[i][j], 0, 0, 0);
  };

  stage(0, 0);            // oldest 4 outstanding
  stage(1, 1);            // newest 4 outstanding
#pragma unroll 1
  for (int kt = 0; kt < NT - 1; ++kt) {
    asm volatile("s_waitcnt vmcnt(4)" ::: "memory");  // slice kt done; kt+1 in flight
    asm volatile("s_barrier" ::: "memory");
    if (kt + 2 < NT) stage(kt + 2, (kt + 2) % 3);     // early issue: overlaps compute(kt)
    __builtin_amdgcn_sched_barrier(0);
    compute(&buf[kt % 3][0]);
  }
  asm volatile("s_waitcnt vmcnt(0)" ::: "memory");
  asm volatile("s_barrier" ::: "memory");
  compute(&buf[(NT - 1) % 3][0]);

  float bj[4];
#pragma unroll
  for (int j = 0; j < 4; ++j) bj[j] = bias[e * NDIM + n0 + wn * 64 + j * 16 + lm];
#pragma unroll
  for (int i = 0; i < 4; ++i)
#pragma unroll
    for (int r = 0; r < 4; ++r) {
      int rabs = tile0 + wm * 64 + i * 16 + lg * 4 + r;   // C/D: row = quad*4 + reg
      if (rabs >= lo && rabs < hi) {
#pragma unroll
        for (int j = 0; j < 4; ++j)
          out[(size_t)rabs * NDIM + n0 + wn * 64 + j * 16 + lm] = acc[i][j][r] + bj[j];
      }
    }
}

// ---------------- two-kernel fallback (round-10 proven path) ----------------
__global__ __launch_bounds__(256) void prepass(
    const float* __restrict__ x, const float* __restrict__ W,
    __bf16* __restrict__ swA, __bf16* __restrict__ swB)
{
  __shared__ __align__(16) __bf16 Lt[64 * 72];
  const int t = threadIdx.x;
  if (blockIdx.x < 1024) {
#pragma unroll
    for (int p = 0; p < 4; ++p) {
      int s = blockIdx.x * 1024 + p * 256 + t;
      int lane = s & 63, kt = (s >> 6) & 31, panel = s >> 11;
      int row = panel * 16 + (lane & 15);
      int k0 = kt * 32 + ((lane >> 4) << 3);
      const float* xp = x + (size_t)row * KDIM + k0;
      float4 a = *(const float4*)xp;
      float4 b = *(const float4*)(xp + 4);
      bf16x8 v;
      v[0] = (__bf16)a.x; v[1] = (__bf16)a.y; v[2] = (__bf16)a.z; v[3] = (__bf16)a.w;
      v[4] = (__bf16)b.x; v[5] = (__bf16)b.y; v[6] = (__bf16)b.z; v[7] = (__bf16)b.w;
      *(bf16x8*)(swA + (size_t)s * 8) = v;
    }
  } else {
    int bid = blockIdx.x - 1024;
    int e = bid >> 8, r = bid & 255;
    int k0 = (r >> 4) * 64, n0 = (r & 15) * 64;
    const float* Wp = W + (size_t)e * KDIM * NDIM;
    int rr0 = t >> 4, c4 = t & 15;
#pragma unroll
    for (int p = 0; p < 4; ++p) {
      int kk = rr0 + p * 16;
      float4 v = *(const float4*)(Wp + (size_t)(k0 + kk) * NDIM + n0 + c4 * 4);
      Lt[(c4 * 4 + 0) * 72 + kk] = (__bf16)v.x;
      Lt[(c4 * 4 + 1) * 72 + kk] = (__bf16)v.y;
      Lt[(c4 * 4 + 2) * 72 + kk] = (__bf16)v.z;
      Lt[(c4 * 4 + 3) * 72 + kk] = (__bf16)v.w;
    }
    __syncthreads();
#pragma unroll
    for (int q = 0; q < 2; ++q) {
      int slot = q * 256 + t;
      int lane = slot & 63, grp = slot >> 6;
      int np = grp & 3, kt2 = grp >> 2;
      int nl = np * 16 + (lane & 15);
      int kl = kt2 * 32 + ((lane >> 4) << 3);
      bf16x8 v = *(const bf16x8*)(Lt + nl * 72 + kl);
      int panel = (n0 >> 4) + np;
      int ktg = (k0 >> 5) + kt2;
      size_t sg = (((size_t)e * 64 + panel) * 32 + ktg) * 64 + lane;
      *(bf16x8*)(swB + sg * 8) = v;
    }
  }
}

__global__ __launch_bounds__(256, 3) void moe_gemm_lds(
    const __bf16* __restrict__ swA, const __bf16* __restrict__ swB,
    const int* __restrict__ gs, const float* __restrict__ bias,
    float* __restrict__ out)
{
  __shared__ __align__(16) __bf16 buf[3][8192];

  const int b = blockIdx.x;
  const int xcd = b & 7, bi = b >> 3;
  int y = xcd * 9 + bi % 9;
  const int nt = bi / 9;

  int e = 0, tile0 = 0, lo = 0, hi = 0, found = 0, off = 0;
#pragma unroll
  for (int i = 0; i < NEXP; ++i) {
    int g = gs[i];
    int first = off >> 7;
    int cnt = (g > 0) ? (((off + g - 1) >> 7) - first + 1) : 0;
    if (!found) {
      if (y < cnt) {
        found = 1; e = i; tile0 = (first + y) << 7;
        lo = max(tile0, off); hi = min(tile0 + 128, off + g);
      } else y -= cnt;
    }
    off += g;
  }
  if (!found) return;
  const int n0 = nt * 128;

  const int t = threadIdx.x, lane = t & 63, wv = t >> 6;
  const int wm = wv & 1, wn = wv >> 1, lm = lane & 15, lg = lane >> 4;

  const __bf16* gA0 = swA + (size_t)((tile0 >> 4) + wv) * 16384 + lane * 8;
  const __bf16* gA1 = swA + (size_t)((tile0 >> 4) + 4 + wv) * 16384 + lane * 8;
  const __bf16* gB0 = swB + (size_t)(e * 64 + (n0 >> 4) + wv) * 16384 + lane * 8;
  const __bf16* gB1 = swB + (size_t)(e * 64 + (n0 >> 4) + 4 + wv) * 16384 + lane * 8;

  auto stage = [&](int kt, int sb) {
    __bf16* l = &buf[sb][0];
    const int ko = kt * 512;
    gl2lds16(gA0 + ko, l + (size_t)(0 * 256 + wv * 64) * 8);
    gl2lds16(gA1 + ko, l + (size_t)(1 * 256 + wv * 64) * 8);
    gl2lds16(gB0 + ko, l + (size_t)(2 * 256 + wv * 64) * 8);
    gl2lds16(gB1 + ko, l + (size_t)(3 * 256 + wv * 64) * 8);
  };

  f32x4 acc[4][4] = {};
  auto compute = [&](const __bf16* l) {
    bf16x8 aF[4], bF[4];
#pragma unroll
    for (int i = 0; i < 4; ++i)
      aF[i] = *(const bf16x8*)(l + (size_t)((wm * 4 + i) * 64 + lane) * 8);
#pragma unroll
    for (int j = 0; j < 4; ++j)
      bF[j] = *(const bf16x8*)(l + 4096 + (size_t)((wn * 4 + j) * 64 + lane) * 8);
#pragma unroll
    for (int i = 0; i < 4; ++i)
#pragma unroll
      for (int j = 0; j < 4; ++j)
        acc[i][j] = __builtin_amdgcn_mfma_f32_16x16x32_bf16(aF[i], bF[j], acc[i][j], 0, 0, 0);
  };

  stage(0, 0);
  stage(1, 1);
#pragma unroll 1
  for (int kt = 0; kt < NT - 1; ++kt) {
    asm volatile("s_waitcnt vmcnt(4)" ::: "memory");
    asm volatile("s_barrier" ::: "memory");
    if (kt + 2 < NT) stage(kt + 2, (kt + 2) % 3);
    __builtin_amdgcn_sched_barrier(0);
    compute(&buf[kt % 3][0]);
  }
  asm volatile("s_waitcnt vmcnt(0)" ::: "memory");
  asm volatile("s_barrier" ::: "memory");
  compute(&buf[(NT - 1) % 3][0]);

  float bj[4];
#pragma unroll
  for (int j = 0; j < 4; ++j) bj[j] = bias[e * NDIM + n0 + wn * 64 + j * 16 + lm];
#pragma unroll
  for (int i = 0; i < 4; ++i)
#pragma unroll
    for (int r = 0; r < 4; ++r) {
      int rabs = tile0 + wm * 64 + i * 16 + lg * 4 + r;
      if (rabs >= lo && rabs < hi) {
#pragma unroll
        for (int j = 0; j < 4; ++j)
          out[(size_t)rabs * NDIM + n0 + wn * 64 + j * 16 + lm] = acc[i][j][r] + bj[j];
      }
    }
}

// ---------------- round-1 fallback (fp32 in-loop conversion) for small ws ----------------
#define LDA 40
__global__ __launch_bounds__(256) void moe_gemm_kernel(
    const float* __restrict__ x, const int* __restrict__ gs,
    const float* __restrict__ W, const float* __restrict__ bias,
    float* __restrict__ out)
{
  __shared__ __bf16 Al[128 * LDA];
  __shared__ __bf16 Bl[128 * LDA];
  const int e = blockIdx.z, mt = blockIdx.y, nt = blockIdx.x;
  int off = 0;
#pragma unroll
  for (int i = 0; i < NEXP; ++i) { int g = gs[i]; if (i < e) off += g; }
  const int ge = gs[e];
  const int m0 = mt * 128;
  if (m0 >= ge) return;
  const int rows = min(128, ge - m0);
  const int row0 = off + m0;
  const int n0 = nt * 128;
  const int t = threadIdx.x, lane = t & 63, wv = t >> 6;
  const int wm = wv & 1, wn = wv >> 1, lm = lane & 15, lg = lane >> 4;
  const int am = t >> 3, kq = t & 7, nb = t & 127, kh = t >> 7;
  float4 aReg[4]; float bReg[16];
  const float* Wp = W + (size_t)e * KDIM * NDIM + n0 + nb;
  auto load_tile = [&](int kt) {
#pragma unroll
    for (int p = 0; p < 4; ++p) {
      int r = am + 32 * p;
      if (r < rows) aReg[p] = *(const float4*)(x + (size_t)(row0 + r) * KDIM + kt * 32 + kq * 4);
      else aReg[p] = make_float4(0.f, 0.f, 0.f, 0.f);
    }
    const float* wp = Wp + (size_t)(kt * 32 + kh * 16) * NDIM;
#pragma unroll
    for (int j = 0; j < 16; ++j) bReg[j] = wp[(size_t)j * NDIM];
  };
  auto store_tile = [&]() {
#pragma unroll
    for (int p = 0; p < 4; ++p) {
      bf16x4 v;
      v[0] = (__bf16)aReg[p].x; v[1] = (__bf16)aReg[p].y;
      v[2] = (__bf16)aReg[p].z; v[3] = (__bf16)aReg[p].w;
      *(bf16x4*)(Al + (am + 32 * p) * LDA + kq * 4) = v;
    }
    bf16x8 b0, b1;
#pragma unroll
    for (int j = 0; j < 8; ++j) { b0[j] = (__bf16)bReg[j]; b1[j] = (__bf16)bReg[8 + j]; }
    *(bf16x8*)(Bl + nb * LDA + kh * 16) = b0;
    *(bf16x8*)(Bl + nb * LDA + kh * 16 + 8) = b1;
  };
  f32x4 acc[4][4] = {};
  load_tile(0);
#pragma unroll 1
  for (int kt = 0; kt < KDIM / 32; ++kt) {
    __syncthreads();
    store_tile();
    __syncthreads();
    if (kt + 1 < KDIM / 32) load_tile(kt + 1);
    bf16x8 af[4], bfr[4];
#pragma unroll
    for (int i = 0; i < 4; ++i)
      af[i] = *(const bf16x8*)(Al + (wm * 64 + i * 16 + lm) * LDA + lg * 8);
#pragma unroll
    for (int j = 0; j < 4; ++j)
      bfr[j] = *(const bf16x8*)(Bl + (wn * 64 + j * 16 + lm) * LDA + lg * 8);
#pragma unroll
    for (int i = 0; i < 4; ++i)
#pragma unroll
      for (int j = 0; j < 4; ++j)
        acc[i][j] = __builtin_amdgcn_mfma_f32_16x16x32_bf16(af[i], bfr[j], acc[i][j], 0, 0, 0);
  }
  float bj[4];
#pragma unroll
  for (int j = 0; j < 4; ++j) bj[j] = bias[e * NDIM + n0 + wn * 64 + j * 16 + lm];
#pragma unroll
  for (int i = 0; i < 4; ++i)
#pragma unroll
    for (int r = 0; r < 4; ++r) {
      int rr = wm * 64 + i * 16 + lg * 4 + r;
      if (rr < rows) {
#pragma unroll
        for (int j = 0; j < 4; ++j)
          out[(size_t)(row0 + rr) * NDIM + n0 + wn * 64 + j * 16 + lm] = acc[i][j][r] + bj[j];
      }
    }
}

extern "C" void kernel_launch(void* const* d_in, const int* in_sizes, int n_in,
                              void* d_out, int out_size, void* d_ws, size_t ws_size,
                              hipStream_t stream) {
  const float* x    = (const float*)d_in[0];
  const int*   gs   = (const int*)d_in[1];
  const float* W    = (const float*)d_in[2];
  const float* bias = (const float*)d_in[3];
  float*       out  = (float*)d_out;

  const size_t swA_bytes = (size_t)TTOK * KDIM * 2;
  const size_t swB_bytes = (size_t)NEXP * KDIM * NDIM * 2;
  if (ws_size >= swA_bytes + swB_bytes) {
    __bf16* swA = (__bf16*)d_ws;
    __bf16* swB = (__bf16*)((char*)d_ws + swA_bytes);
    void* args[] = {(void*)&x, (void*)&W, (void*)&gs, (void*)&bias,
                    (void*)&swA, (void*)&swB, (void*)&out};
    hipError_t err = hipLaunchCooperativeKernel(
        (const void*)moe_fused, dim3(576), dim3(256), args, 0, stream);
    if (err != hipSuccess) {
      // proven two-kernel path (round 10, 132.2 us)
      prepass<<<dim3(1024 + 2048), 256, 0, stream>>>(x, W, swA, swB);
      moe_gemm_lds<<<dim3(576), 256, 0, stream>>>(swA, swB, gs, bias, out);
    }
  } else {
    moe_gemm_kernel<<<dim3(NDIM / 128, TTOK / 128, NEXP), 256, 0, stream>>>(x, gs, W, bias, out);
  }
}

// Round 12
// 131.471 us; speedup vs baseline: 2.2122x; 2.2122x over previous
//
#include <hip/hip_runtime.h>
#include <hip/hip_bf16.h>

#define KDIM 1024
#define NDIM 1024
#define NEXP 8
#define TTOK 8192
#define NT (KDIM / 32)

typedef __bf16 bf16x8 __attribute__((ext_vector_type(8)));
typedef __bf16 bf16x4 __attribute__((ext_vector_type(4)));
typedef float  f32x4  __attribute__((ext_vector_type(4)));

__device__ __forceinline__ void gl2lds16(const void* g, void* l) {
  __builtin_amdgcn_global_load_lds(
      (const __attribute__((address_space(1))) void*)g,
      (__attribute__((address_space(3))) void*)l, 16, 0, 0);
}

// Fragment-swizzled layouts (16B per lane-slot):
//   swA slot(panel,kt,lane) = x[panel*16 + (lane&15)][kt*32 + (lane>>4)*8 .. +8]
//   swB slot(e,panel,kt,lane) = W[e][kt*32 + (lane>>4)*8 .. +8][panel*16 + (lane&15)]

// ---------------- prepass: build swA (x fp32->bf16) and swB (W transpose) ----------------
// Runs as 3072 independent blocks: TLP is the latency-hider (r11 lesson: grid-striding
// this into 576 co-resident blocks drops it to 0.6 TB/s).
__global__ __launch_bounds__(256) void prepass(
    const float* __restrict__ x, const float* __restrict__ W,
    __bf16* __restrict__ swA, __bf16* __restrict__ swB)
{
  __shared__ __align__(16) __bf16 Lt[64 * 72];
  const int t = threadIdx.x;
  if (blockIdx.x < 1024) {
#pragma unroll
    for (int p = 0; p < 4; ++p) {
      int s = blockIdx.x * 1024 + p * 256 + t;
      int lane = s & 63, kt = (s >> 6) & 31, panel = s >> 11;
      int row = panel * 16 + (lane & 15);
      int k0 = kt * 32 + ((lane >> 4) << 3);
      const float* xp = x + (size_t)row * KDIM + k0;
      float4 a = *(const float4*)xp;
      float4 b = *(const float4*)(xp + 4);
      bf16x8 v;
      v[0] = (__bf16)a.x; v[1] = (__bf16)a.y; v[2] = (__bf16)a.z; v[3] = (__bf16)a.w;
      v[4] = (__bf16)b.x; v[5] = (__bf16)b.y; v[6] = (__bf16)b.z; v[7] = (__bf16)b.w;
      *(bf16x8*)(swA + (size_t)s * 8) = v;
    }
  } else {
    int bid = blockIdx.x - 1024;
    int e = bid >> 8, r = bid & 255;
    int k0 = (r >> 4) * 64, n0 = (r & 15) * 64;
    const float* Wp = W + (size_t)e * KDIM * NDIM;
    int rr0 = t >> 4, c4 = t & 15;
#pragma unroll
    for (int p = 0; p < 4; ++p) {
      int kk = rr0 + p * 16;
      float4 v = *(const float4*)(Wp + (size_t)(k0 + kk) * NDIM + n0 + c4 * 4);
      Lt[(c4 * 4 + 0) * 72 + kk] = (__bf16)v.x;
      Lt[(c4 * 4 + 1) * 72 + kk] = (__bf16)v.y;
      Lt[(c4 * 4 + 2) * 72 + kk] = (__bf16)v.z;
      Lt[(c4 * 4 + 3) * 72 + kk] = (__bf16)v.w;
    }
    __syncthreads();
#pragma unroll
    for (int q = 0; q < 2; ++q) {
      int slot = q * 256 + t;
      int lane = slot & 63, grp = slot >> 6;
      int np = grp & 3, kt2 = grp >> 2;
      int nl = np * 16 + (lane & 15);
      int kl = kt2 * 32 + ((lane >> 4) << 3);
      bf16x8 v = *(const bf16x8*)(Lt + nl * 72 + kl);
      int panel = (n0 >> 4) + np;
      int ktg = (k0 >> 5) + kt2;
      size_t sg = (((size_t)e * 64 + panel) * 32 + ktg) * 64 + lane;
      *(bf16x8*)(swB + sg * 8) = v;
    }
  }
}

// ---------------- GEMM: proven config (132.2 us, round 10) ----------------
// Structural requirements established r1-r11: bf16 A+B via gl2lds (zero-register
// staging), 3 LDS buffers (depth-2), 3 blocks/CU (inter-block TLP is the latency
// hider), XCD-contiguous m-ownership (A L2-residency), counted vmcnt(4) never
// draining mid-loop. Every departure measured slower.
__global__ __launch_bounds__(256, 3) void moe_gemm_lds(
    const __bf16* __restrict__ swA, const __bf16* __restrict__ swB,
    const int* __restrict__ gs, const float* __restrict__ bias,
    float* __restrict__ out)
{
  __shared__ __align__(16) __bf16 buf[3][8192];   // 3 x 16 KB (A slots 0..511, B 512..1023)

  const int b = blockIdx.x;
  const int xcd = b & 7, bi = b >> 3;
  int y = xcd * 9 + bi % 9;           // global m-tile index (XCD-contiguous m-ranges)
  const int nt = bi / 9;

  int e = 0, tile0 = 0, lo = 0, hi = 0, found = 0, off = 0;
#pragma unroll
  for (int i = 0; i < NEXP; ++i) {
    int g = gs[i];
    int first = off >> 7;
    int cnt = (g > 0) ? (((off + g - 1) >> 7) - first + 1) : 0;
    if (!found) {
      if (y < cnt) {
        found = 1; e = i; tile0 = (first + y) << 7;
        lo = max(tile0, off); hi = min(tile0 + 128, off + g);
      } else y -= cnt;
    }
    off += g;
  }
  if (!found) return;                       // block-uniform: no barrier mismatch
  const int n0 = nt * 128;

  const int t = threadIdx.x, lane = t & 63, wv = t >> 6;
  const int wm = wv & 1, wn = wv >> 1, lm = lane & 15, lg = lane >> 4;

  // staging sources: wave wv stages A panels {wv, 4+wv} and B panels {wv, 4+wv}
  const __bf16* gA0 = swA + (size_t)((tile0 >> 4) + wv) * 16384 + lane * 8;
  const __bf16* gA1 = swA + (size_t)((tile0 >> 4) + 4 + wv) * 16384 + lane * 8;
  const __bf16* gB0 = swB + (size_t)(e * 64 + (n0 >> 4) + wv) * 16384 + lane * 8;
  const __bf16* gB1 = swB + (size_t)(e * 64 + (n0 >> 4) + 4 + wv) * 16384 + lane * 8;

  auto stage = [&](int kt, int sb) {
    __bf16* l = &buf[sb][0];
    const int ko = kt * 512;
    gl2lds16(gA0 + ko, l + (size_t)(0 * 256 + wv * 64) * 8);   // A panel wv
    gl2lds16(gA1 + ko, l + (size_t)(1 * 256 + wv * 64) * 8);   // A panel 4+wv
    gl2lds16(gB0 + ko, l + (size_t)(2 * 256 + wv * 64) * 8);   // B panel wv
    gl2lds16(gB1 + ko, l + (size_t)(3 * 256 + wv * 64) * 8);   // B panel 4+wv
  };

  f32x4 acc[4][4] = {};
  auto compute = [&](const __bf16* l) {
    bf16x8 aF[4], bF[4];
#pragma unroll
    for (int i = 0; i < 4; ++i)
      aF[i] = *(const bf16x8*)(l + (size_t)((wm * 4 + i) * 64 + lane) * 8);
#pragma unroll
    for (int j = 0; j < 4; ++j)
      bF[j] = *(const bf16x8*)(l + 4096 + (size_t)((wn * 4 + j) * 64 + lane) * 8);
#pragma unroll
    for (int i = 0; i < 4; ++i)
#pragma unroll
      for (int j = 0; j < 4; ++j)
        acc[i][j] = __builtin_amdgcn_mfma_f32_16x16x32_bf16(aF[i], bF[j], acc[i][j], 0, 0, 0);
  };

  stage(0, 0);            // oldest 4 outstanding
  stage(1, 1);            // newest 4 outstanding
#pragma unroll 1
  for (int kt = 0; kt < NT - 1; ++kt) {
    asm volatile("s_waitcnt vmcnt(4)" ::: "memory");  // slice kt done; kt+1 in flight
    asm volatile("s_barrier" ::: "memory");
    if (kt + 2 < NT) stage(kt + 2, (kt + 2) % 3);     // early issue: overlaps compute(kt)
    __builtin_amdgcn_sched_barrier(0);
    compute(&buf[kt % 3][0]);
  }
  asm volatile("s_waitcnt vmcnt(0)" ::: "memory");    // final slice: drain
  asm volatile("s_barrier" ::: "memory");
  compute(&buf[(NT - 1) % 3][0]);

  float bj[4];
#pragma unroll
  for (int j = 0; j < 4; ++j) bj[j] = bias[e * NDIM + n0 + wn * 64 + j * 16 + lm];
#pragma unroll
  for (int i = 0; i < 4; ++i)
#pragma unroll
    for (int r = 0; r < 4; ++r) {
      int rabs = tile0 + wm * 64 + i * 16 + lg * 4 + r;   // C/D: row = quad*4 + reg
      if (rabs >= lo && rabs < hi) {
#pragma unroll
        for (int j = 0; j < 4; ++j)
          out[(size_t)rabs * NDIM + n0 + wn * 64 + j * 16 + lm] = acc[i][j][r] + bj[j];
      }
    }
}

// ---------------- fallback (fp32 in-loop conversion) for small ws ----------------
#define LDA 40
__global__ __launch_bounds__(256) void moe_gemm_kernel(
    const float* __restrict__ x, const int* __restrict__ gs,
    const float* __restrict__ W, const float* __restrict__ bias,
    float* __restrict__ out)
{
  __shared__ __bf16 Al[128 * LDA];
  __shared__ __bf16 Bl[128 * LDA];
  const int e = blockIdx.z, mt = blockIdx.y, nt = blockIdx.x;
  int off = 0;
#pragma unroll
  for (int i = 0; i < NEXP; ++i) { int g = gs[i]; if (i < e) off += g; }
  const int ge = gs[e];
  const int m0 = mt * 128;
  if (m0 >= ge) return;
  const int rows = min(128, ge - m0);
  const int row0 = off + m0;
  const int n0 = nt * 128;
  const int t = threadIdx.x, lane = t & 63, wv = t >> 6;
  const int wm = wv & 1, wn = wv >> 1, lm = lane & 15, lg = lane >> 4;
  const int am = t >> 3, kq = t & 7, nb = t & 127, kh = t >> 7;
  float4 aReg[4]; float bReg[16];
  const float* Wp = W + (size_t)e * KDIM * NDIM + n0 + nb;
  auto load_tile = [&](int kt) {
#pragma unroll
    for (int p = 0; p < 4; ++p) {
      int r = am + 32 * p;
      if (r < rows) aReg[p] = *(const float4*)(x + (size_t)(row0 + r) * KDIM + kt * 32 + kq * 4);
      else aReg[p] = make_float4(0.f, 0.f, 0.f, 0.f);
    }
    const float* wp = Wp + (size_t)(kt * 32 + kh * 16) * NDIM;
#pragma unroll
    for (int j = 0; j < 16; ++j) bReg[j] = wp[(size_t)j * NDIM];
  };
  auto store_tile = [&]() {
#pragma unroll
    for (int p = 0; p < 4; ++p) {
      bf16x4 v;
      v[0] = (__bf16)aReg[p].x; v[1] = (__bf16)aReg[p].y;
      v[2] = (__bf16)aReg[p].z; v[3] = (__bf16)aReg[p].w;
      *(bf16x4*)(Al + (am + 32 * p) * LDA + kq * 4) = v;
    }
    bf16x8 b0, b1;
#pragma unroll
    for (int j = 0; j < 8; ++j) { b0[j] = (__bf16)bReg[j]; b1[j] = (__bf16)bReg[8 + j]; }
    *(bf16x8*)(Bl + nb * LDA + kh * 16) = b0;
    *(bf16x8*)(Bl + nb * LDA + kh * 16 + 8) = b1;
  };
  f32x4 acc[4][4] = {};
  load_tile(0);
#pragma unroll 1
  for (int kt = 0; kt < KDIM / 32; ++kt) {
    __syncthreads();
    store_tile();
    __syncthreads();
    if (kt + 1 < KDIM / 32) load_tile(kt + 1);
    bf16x8 af[4], bfr[4];
#pragma unroll
    for (int i = 0; i < 4; ++i)
      af[i] = *(const bf16x8*)(Al + (wm * 64 + i * 16 + lm) * LDA + lg * 8);
#pragma unroll
    for (int j = 0; j < 4; ++j)
      bfr[j] = *(const bf16x8*)(Bl + (wn * 64 + j * 16 + lm) * LDA + lg * 8);
#pragma unroll
    for (int i = 0; i < 4; ++i)
#pragma unroll
      for (int j = 0; j < 4; ++j)
        acc[i][j] = __builtin_amdgcn_mfma_f32_16x16x32_bf16(af[i], bfr[j], acc[i][j], 0, 0, 0);
  }
  float bj[4];
#pragma unroll
  for (int j = 0; j < 4; ++j) bj[j] = bias[e * NDIM + n0 + wn * 64 + j * 16 + lm];
#pragma unroll
  for (int i = 0; i < 4; ++i)
#pragma unroll
    for (int r = 0; r < 4; ++r) {
      int rr = wm * 64 + i * 16 + lg * 4 + r;
      if (rr < rows) {
#pragma unroll
        for (int j = 0; j < 4; ++j)
          out[(size_t)(row0 + rr) * NDIM + n0 + wn * 64 + j * 16 + lm] = acc[i][j][r] + bj[j];
      }
    }
}

extern "C" void kernel_launch(void* const* d_in, const int* in_sizes, int n_in,
                              void* d_out, int out_size, void* d_ws, size_t ws_size,
                              hipStream_t stream) {
  const float* x    = (const float*)d_in[0];
  const int*   gs   = (const int*)d_in[1];
  const float* W    = (const float*)d_in[2];
  const float* bias = (const float*)d_in[3];
  float*       out  = (float*)d_out;

  const size_t swA_bytes = (size_t)TTOK * KDIM * 2;
  const size_t swB_bytes = (size_t)NEXP * KDIM * NDIM * 2;
  if (ws_size >= swA_bytes + swB_bytes) {
    __bf16* swA = (__bf16*)d_ws;
    __bf16* swB = (__bf16*)((char*)d_ws + swA_bytes);
    prepass<<<dim3(1024 + 2048), 256, 0, stream>>>(x, W, swA, swB);
    // 1D grid, XCD-contiguous m-ranges: xcd=b&7 owns m-tiles [9*xcd, 9*xcd+9) x all n.
    moe_gemm_lds<<<dim3(576), 256, 0, stream>>>(swA, swB, gs, bias, out);
  } else {
    moe_gemm_kernel<<<dim3(NDIM / 128, TTOK / 128, NEXP), 256, 0, stream>>>(x, gs, W, bias, out);
  }
}